// Round 1
// baseline (111.868 us; speedup 1.0000x reference)
//
#include <hip/hip_runtime.h>

// MXIntSoftmax (MASE-style hardware softmax emulation), bit-exact integer port.
//
// Reference semantics collapsed:
//   per element: e = clip(ceil(log2|x|),-8,7); m = clip(rne(x*2^(7-e)),-128,127)
//                y32 = m*46*2^(e-7)  (exact in f32); yq = clip(floor(y32),-256,255)
//                n = yq>>5; mexp = TAB[yq&31] in [64,127]; M = 16*mexp
//   scan (sequential w/ floors) == single floor:
//                E_i = prefix-max(e), S = sum_i ((M_i >> (E_i-e_i)) << (E_i+8))
//                mexp_sum = S >> (E*+8)   (int64 sum; >= 1024 always)
//   out: mout = (mexp<<8)/mexp_sum (in [0,31]); q = mout*2^(e_i-E*-4); mxint_quant(q,8,4)
//       done in integer/bit math (half-even, 128->127 clip, e clip at -8).

#define D_DIM 2048
#define TPB   256
#define EPT   8

__device__ __constant__ int c_mexp_tab[32] = {
    64, 65, 67, 68, 70, 71, 73, 74, 76, 78, 79, 81, 83, 85, 87, 89,
    91, 92, 95, 97, 99, 101, 103, 105, 108, 110, 112, 115, 117, 120, 123, 125
};

__global__ __launch_bounds__(TPB) void mxint_softmax_kernel(const float* __restrict__ x,
                                                            float* __restrict__ out) {
    const int t    = threadIdx.x;
    const int row  = blockIdx.x;
    const int lane = t & 63;
    const int wid  = t >> 6;

    __shared__ int       s_tab[32];
    __shared__ int       s_wmax[4];
    __shared__ long long s_wsum[4];

    if (t < 32) s_tab[t] = c_mexp_tab[t];
    __syncthreads();

    const size_t base = (size_t)row * D_DIM + (size_t)t * EPT;
    const float4 v0 = *(const float4*)(x + base);
    const float4 v1 = *(const float4*)(x + base + 4);
    float xs[8] = {v0.x, v0.y, v0.z, v0.w, v1.x, v1.y, v1.z, v1.w};

    int me[8], ee[8], lp[8];
    int run = -1000;
#pragma unroll
    for (int j = 0; j < 8; ++j) {
        const float xv = xs[j];
        const unsigned bits  = __float_as_uint(xv) & 0x7fffffffu;
        const int      ebits = (int)(bits >> 23);
        const unsigned mant  = bits & 0x7fffffu;
        // ceil(log2|x|): exact power of two -> ebits-127, else ebits-126; 0/subnormal -> very small
        int e = (ebits == 0) ? -1000 : ((mant == 0) ? (ebits - 127) : (ebits - 126));
        e = min(7, max(-8, e));
        const float scale_up = __uint_as_float((unsigned)(7 - e + 127) << 23);   // 2^(7-e), exact
        float m = rintf(xv * scale_up);                                          // half-to-even
        m = fminf(127.0f, fmaxf(-128.0f, m));
        const float scale_dn = __uint_as_float((unsigned)(e - 7 + 127) << 23);   // 2^(e-7), exact
        const float y32 = m * 46.0f * scale_dn;    // == qx*1.4375*32, exact in f32
        int yq = (int)floorf(y32);
        yq = min(255, max(-256, yq));
        ee[j] = yq >> 5;            // floor(yq/32), arithmetic shift
        me[j] = s_tab[yq & 31];
        run   = max(run, ee[j]);
        lp[j] = run;                // local inclusive prefix max
    }

    // ---- exclusive prefix max across the block (thread order == element order) ----
    int v = run;
#pragma unroll
    for (int d = 1; d < 64; d <<= 1) {
        const int o = __shfl_up(v, d, 64);
        if (lane >= d) v = max(v, o);
    }
    if (lane == 63) s_wmax[wid] = v;     // per-wave max
    __syncthreads();
    int wpref = -1000;
#pragma unroll
    for (int w = 0; w < 4; ++w)
        if (w < wid) wpref = max(wpref, s_wmax[w]);
    int excl_wave = __shfl_up(v, 1, 64);
    if (lane == 0) excl_wave = -1000;
    const int P = max(wpref, excl_wave);  // exclusive prefix max for this thread

    // ---- weighted integer sum (collapsed scan) ----
    long long partial = 0;
#pragma unroll
    for (int j = 0; j < 8; ++j) {
        const int E  = max(P, lp[j]);
        const int sh = E - ee[j];                 // 0..15
        const int c  = (me[j] << 4) >> sh;        // floor(M * 2^(e-E))
        partial += (long long)c << (E + 8);       // E+8 in [0,15]
    }
#pragma unroll
    for (int d = 32; d >= 1; d >>= 1) partial += __shfl_down(partial, d, 64);
    if (lane == 0) s_wsum[wid] = partial;
    __syncthreads();

    const long long total = s_wsum[0] + s_wsum[1] + s_wsum[2] + s_wsum[3];
    const int Estar = max(max(s_wmax[0], s_wmax[1]), max(s_wmax[2], s_wmax[3]));
    const unsigned msum = (unsigned)(total >> (Estar + 8));   // >= 1024

    // ---- per-element division + final mxint quant (exact integer path) ----
    float res[8];
#pragma unroll
    for (int j = 0; j < 8; ++j) {
        const unsigned mout = ((unsigned)me[j] << 8) / msum;  // in [0,31]
        float o = 0.0f;
        if (mout != 0u) {
            const int  eout = ee[j] - Estar;                  // [-15, 0]
            const int  bl   = 32 - __clz(mout);
            const bool pw2  = (mout & (mout - 1u)) == 0u;
            const int  clog = pw2 ? (bl - 1) : bl;            // ceil(log2(mout)) in [0,5]
            const int  e2   = clog + eout - 4;                // true exponent
            int m2, e2c;
            if (e2 >= -8) {
                e2c = e2;
                m2  = pw2 ? 127 : (int)(mout << (7 - clog));  // in (64,128); 128 clips to 127
            } else {
                e2c = -8;
                const int sh = eout + 11;                     // m2 = rne(mout * 2^sh)
                if (sh >= 0) {
                    m2 = (int)(mout << sh);                   // < 128
                } else {
                    const int      s2   = -sh;
                    const unsigned bse  = mout >> s2;
                    const unsigned frac = mout & ((1u << s2) - 1u);
                    const unsigned half = 1u << (s2 - 1);
                    m2 = (int)(bse + ((frac > half || (frac == half && (bse & 1u))) ? 1u : 0u));
                }
            }
            o = (float)m2 * __uint_as_float((unsigned)(e2c - 7 + 127) << 23);  // m2*2^(e2c-7)
        }
        res[j] = o;
    }

    float4 r0 = {res[0], res[1], res[2], res[3]};
    float4 r1 = {res[4], res[5], res[6], res[7]};
    *(float4*)(out + base)     = r0;
    *(float4*)(out + base + 4) = r1;
}

extern "C" void kernel_launch(void* const* d_in, const int* in_sizes, int n_in,
                              void* d_out, int out_size, void* d_ws, size_t ws_size,
                              hipStream_t stream) {
    const float* x   = (const float*)d_in[0];
    float*       out = (float*)d_out;
    const int rows = in_sizes[0] / D_DIM;   // 8192
    mxint_softmax_kernel<<<rows, TPB, 0, stream>>>(x, out);
}